// Round 17
// baseline (179.773 us; speedup 1.0000x reference)
//
#include <hip/hip_runtime.h>

#define H 128
#define NHEADS 8
#define SQ 4096
#define HD 1024   // NHEADS*H

typedef float f32x4 __attribute__((ext_vector_type(4)));
typedef __bf16 bf16x8 __attribute__((ext_vector_type(8)));
typedef unsigned short u16x4 __attribute__((ext_vector_type(4)));
typedef unsigned short u16x8 __attribute__((ext_vector_type(8)));
typedef unsigned int u32x4 __attribute__((ext_vector_type(4)));

static __device__ __forceinline__ unsigned short f2bf(float f) {
  unsigned int u = __builtin_bit_cast(unsigned int, f);
  u += 0x7fffu + ((u >> 16) & 1u);           // round-nearest-even
  return (unsigned short)(u >> 16);
}
static __device__ __forceinline__ float b2f(unsigned short s) {
  unsigned int u = (unsigned int)s << 16;
  return __builtin_bit_cast(float, u);
}
static __device__ __forceinline__ bf16x8 ld_bf8(const unsigned short* p) {
  return __builtin_bit_cast(bf16x8, *(const u16x8*)p);
}

// async global->LDS DMA, 16B per lane; dest = wave-uniform base + lane*16.
#define GLOAD_LDS16(gp, lp)                                        \
  __builtin_amdgcn_global_load_lds(                                \
      (__attribute__((address_space(1))) void*)(gp),               \
      (__attribute__((address_space(3))) void*)(lp), 16, 0, 0)

// ---------------- kernel 0: weight transpose+convert, LDS-tiled -----------
// grid 64. Blocks 0..31: W1+W2; 32..63: Wc. 64x64 tiles; pitch 66 (scalar
// 2B accesses only -- the b128 16-byte-alignment rule does not apply here).
__global__ __launch_bounds__(256) void prep_kernel(
    const float* __restrict__ W1, const float* __restrict__ W2,
    const float* __restrict__ Wc,
    unsigned short* __restrict__ W1T, unsigned short* __restrict__ W2T,
    unsigned short* __restrict__ WcT)
{
  __shared__ unsigned short tile[64 * 66];
  const int b = blockIdx.x, tid = threadIdx.x;
  if (b < 32) {
    const int k0 = (b & 1) * 64, n0 = (b >> 1) * 64;
    for (int i = 0; i < 16; ++i) {
      int idx = tid + i * 256;
      int r = idx >> 6, cc = idx & 63;       // r = k-local, cc = n-local
      tile[cc * 66 + r] = f2bf(W1[(size_t)(k0 + r) * HD + n0 + cc]);
    }
    __syncthreads();
    for (int i = 0; i < 16; ++i) {
      int idx = tid + i * 256;
      int r = idx >> 6, cc = idx & 63;       // r = n-local, cc = k-local
      W1T[(size_t)(n0 + r) * H + k0 + cc] = tile[r * 66 + cc];
    }
    __syncthreads();
    for (int i = 0; i < 16; ++i) {
      int idx = tid + i * 256;
      int r = idx >> 6, cc = idx & 63;
      tile[cc * 66 + r] = f2bf(W2[(size_t)(k0 + r) * HD + n0 + cc]);
    }
    __syncthreads();
    for (int i = 0; i < 16; ++i) {
      int idx = tid + i * 256;
      int r = idx >> 6, cc = idx & 63;
      W2T[(size_t)(n0 + r) * H + k0 + cc] = tile[r * 66 + cc];
    }
  } else {
    const int bb = b - 32;
    const int n0 = (bb & 1) * 64, k0 = (bb >> 1) * 64;
    for (int i = 0; i < 16; ++i) {
      int idx = tid + i * 256;
      int r = idx >> 6, cc = idx & 63;       // r = k-local, cc = n-local
      tile[cc * 66 + r] = f2bf(Wc[(size_t)(k0 + r) * H + n0 + cc]);
    }
    __syncthreads();
    for (int i = 0; i < 16; ++i) {
      int idx = tid + i * 256;
      int r = idx >> 6, cc = idx & 63;       // r = n-local, cc = k-local
      WcT[(size_t)(n0 + r) * HD + k0 + cc] = tile[r * 66 + cc];
    }
  }
}

// ---------------- kernel 1: q1/q2 projection, coalesced stores ------------
__global__ __launch_bounds__(256) void proj_kernel(
    const float* __restrict__ x,
    const float* __restrict__ b1, const float* __restrict__ b2,
    const unsigned short* __restrict__ W1T, const unsigned short* __restrict__ W2T,
    unsigned short* __restrict__ q1bf, unsigned short* __restrict__ q2K,
    unsigned short* __restrict__ q2VT)
{
  __shared__ unsigned short At[64 * 136];
  __shared__ unsigned short Bt[128 * 136];
  const int tid = threadIdx.x;
  const int st = blockIdx.x & 63, h = blockIdx.x >> 6;
  const int s0 = st * 64;
  const int lane = tid & 63, w = tid >> 6;
  const int c = lane & 15, q4 = lane >> 4;

  for (int i = 0; i < 4; ++i) {
    int ch = tid + i * 256;
    int row = ch >> 4, col8 = (ch & 15) * 8;
    const float* gp = x + (s0 + row) * H + col8;
    f32x4 a = *(const f32x4*)gp;
    f32x4 b = *(const f32x4*)(gp + 4);
    u16x8 v;
    v[0]=f2bf(a[0]); v[1]=f2bf(a[1]); v[2]=f2bf(a[2]); v[3]=f2bf(a[3]);
    v[4]=f2bf(b[0]); v[5]=f2bf(b[1]); v[6]=f2bf(b[2]); v[7]=f2bf(b[3]);
    *(u16x8*)&At[row * 136 + col8] = v;
  }
  for (int i = 0; i < 8; ++i) {
    int ch = tid + i * 256;
    int row = ch >> 4, col8 = (ch & 15) * 8;
    *(u16x8*)&Bt[row * 136 + col8] = *(const u16x8*)&W1T[(h * H + row) * H + col8];
  }
  __syncthreads();                           // S1

  bf16x8 af[4];                              // A-frags (reused for q1 and q2)
  for (int kc = 0; kc < 4; ++kc)
    af[kc] = ld_bf8(&At[(w * 16 + c) * 136 + kc * 32 + q4 * 8]);
  __syncthreads();                           // S2: all af hoisted; At reusable

  // q1 = x @ W1 + b1 -> stage into At as [s-local][d]
  for (int nt = 0; nt < 8; ++nt) {
    f32x4 acc = {0.f, 0.f, 0.f, 0.f};
    for (int kc = 0; kc < 4; ++kc) {
      bf16x8 bf = ld_bf8(&Bt[(nt * 16 + c) * 136 + kc * 32 + q4 * 8]);
      acc = __builtin_amdgcn_mfma_f32_16x16x32_bf16(af[kc], bf, acc, 0, 0, 0);
    }
    float bb = b1[h * H + nt * 16 + c];
    for (int r = 0; r < 4; ++r)
      At[(w * 16 + q4 * 4 + r) * 136 + nt * 16 + c] = f2bf(acc[r] + bb);
  }
  __syncthreads();                           // S3

  for (int i = 0; i < 4; ++i) {
    int ch = tid + i * 256;
    int row = ch >> 4, col8 = (ch & 15) * 8;
    *(u16x8*)&q1bf[(size_t)(h * SQ + s0 + row) * H + col8] =
        *(const u16x8*)&At[row * 136 + col8];
  }
  for (int i = 0; i < 8; ++i) {
    int ch = tid + i * 256;
    int row = ch >> 4, col8 = (ch & 15) * 8;
    *(u16x8*)&Bt[row * 136 + col8] = *(const u16x8*)&W2T[(h * H + row) * H + col8];
  }
  __syncthreads();                           // S4

  f32x4 q2a[8];
  for (int nt = 0; nt < 8; ++nt) {
    f32x4 acc = {0.f, 0.f, 0.f, 0.f};
    for (int kc = 0; kc < 4; ++kc) {
      bf16x8 bf = ld_bf8(&Bt[(nt * 16 + c) * 136 + kc * 32 + q4 * 8]);
      acc = __builtin_amdgcn_mfma_f32_16x16x32_bf16(af[kc], bf, acc, 0, 0, 0);
    }
    q2a[nt] = acc;
  }
  __syncthreads();                           // S5

  for (int nt = 0; nt < 8; ++nt) {
    float bb = b2[h * H + nt * 16 + c];
    unsigned short vs[4];
    for (int r = 0; r < 4; ++r) {
      unsigned short u = f2bf(q2a[nt][r] + bb);
      At[(w * 16 + q4 * 4 + r) * 136 + nt * 16 + c] = u;
      vs[r] = u;
    }
    u16x4 v4 = {vs[0], vs[1], vs[2], vs[3]};
    *(u16x4*)&Bt[(nt * 16 + c) * 72 + w * 16 + q4 * 4] = v4;
  }
  __syncthreads();                           // S6

  for (int i = 0; i < 4; ++i) {
    int ch = tid + i * 256;
    int row = ch >> 4, col8 = (ch & 15) * 8;
    *(u16x8*)&q2K[(size_t)(h * SQ + s0 + row) * H + col8] =
        *(const u16x8*)&At[row * 136 + col8];
  }
  for (int i = 0; i < 4; ++i) {
    int ch = tid + i * 256;
    int row = ch >> 3, col8 = (ch & 7) * 8;  // row = d 0..127
    *(u16x8*)&q2VT[(size_t)(h * H + row) * SQ + s0 + col8] =
        *(const u16x8*)&Bt[row * 72 + col8];
  }
}

// ---------------- kernel 2: flash attention, 2-way KEY-SPLIT --------------
// R27 = R26 resubmitted (R16 round was a GPU-acquisition timeout, no data).
// R26 = R25 (double-buffered, 1 barrier/kt) + global_load_lds DMA staging.
// Staging (8 global->VGPR loads + 8 ds_write_b128 per thread-kt, ~10% of
// the issue window) is replaced by 8 async DMAs. DMA dest is linear
// (wave-uniform base + lane*16), so the R22-VERIFIED XOR chunk layout is
// produced by pre-swizzling the per-lane GLOBAL source address (rule: swz
// on source + read, LDS linear): LDS(row,chunk) = data[row][chunk^(row&7)].
// Reads use R22's exact (correctness-passed) XOR expressions. Pipeline:
// DMA(buf[cur^1]) issues right after barrier kt (all waves provably done
// reading that buffer at kt-1); the compiler's vmcnt(0)-before-s_barrier
// drains it exactly at barrier kt+1. LDS 71,680 -> 65,536 B; kreg/vreg
// (32 VGPRs) eliminated. Numerics bit-identical (pure data-movement change).
__global__ __launch_bounds__(256, 2) void flash_kernel(
    const unsigned short* __restrict__ q1bf,
    const unsigned short* __restrict__ q2K,
    const unsigned short* __restrict__ q2VT,
    unsigned short* __restrict__ ctxp,   // [kb][s][h*128+d] bf16, local-normed
    float* __restrict__ lbuf)            // [kb][h][s]
{
  __shared__ unsigned short Kt[2][64 * 128];   // [key][chunk^row&7] linear
  __shared__ unsigned short VT[2][128 * 64];   // [d][chunk^row&7]   linear
  const int tid = threadIdx.x;
  const int bid = blockIdx.x;
  const int kb = bid >> 8;                     // key half
  const int h = (bid >> 5) & 7, qb = bid & 31;
  const int s0 = qb * 128;
  const int kbase = kb * 2048;                 // 32 tiles each
  const int lane = tid & 63, w = tid >> 6;
  const int c = lane & 15, q4 = lane >> 4;
  const int wch = tid & 192;                   // wave chunk base (w*64)

  bf16x8 qf[2][4];
  for (int blk = 0; blk < 2; ++blk)
    for (int kc = 0; kc < 4; ++kc)
      qf[blk][kc] = ld_bf8(
          &q1bf[(h * SQ + s0 + w * 32 + blk * 16 + c) * H + kc * 32 + q4 * 8]);

  f32x4 acc[2][8];
  for (int blk = 0; blk < 2; ++blk)
    for (int nt = 0; nt < 8; ++nt) acc[blk][nt] = (f32x4){0.f, 0.f, 0.f, 0.f};
  float lsum[2] = {0.f, 0.f};

  // async-stage tile at key offset k0 into buf: per-lane pre-swizzled
  // global source, linear LDS dest (chunk index == ch).
  auto stage = [&](int buf, int k0) {
#pragma unroll
    for (int i = 0; i < 4; ++i) {
      int ch = tid + i * 256;
      int krow = ch >> 4;
      int kchunk = (ch & 15) ^ (krow & 7);
      GLOAD_LDS16(q2K + (size_t)(h * SQ + k0 + krow) * H + kchunk * 8,
                  &Kt[buf][(i * 256 + wch) * 8]);
      int vrow = ch >> 3;
      int vchunk = (ch & 7) ^ (vrow & 7);
      GLOAD_LDS16(q2VT + (size_t)(h * H + vrow) * SQ + k0 + vchunk * 8,
                  &VT[buf][(i * 256 + wch) * 8]);
    }
  };

  stage(0, kbase);                           // prologue DMA for kt=0

  for (int kt = 0; kt < 32; ++kt) {
    const int cur = kt & 1;
    __syncthreads();                         // drains DMA -> buf[cur] ready

    if (kt < 31)                             // DMA for kt+1, in flight
      stage(cur ^ 1, kbase + (kt + 1) * 64); // under this iter's compute

    f32x4 sc[2][4];
    for (int mt = 0; mt < 4; ++mt) {
      bf16x8 kf[4];
      for (int kc = 0; kc < 4; ++kc) {
        int chunk = (kc * 4 + q4) ^ (c & 7); // R22-verified read swizzle
        kf[kc] = ld_bf8(&Kt[cur][(mt * 16 + c) * 128 + chunk * 8]);
      }
      for (int blk = 0; blk < 2; ++blk) {
        f32x4 s = {0.f, 0.f, 0.f, 0.f};
        for (int kc = 0; kc < 4; ++kc)
          s = __builtin_amdgcn_mfma_f32_16x16x32_bf16(kf[kc], qf[blk][kc], s, 0, 0, 0);
        sc[blk][mt] = s;
      }
    }

    // softmax + plain-C bf16 pack (f2bf == the proven Pb path's rounding)
    unsigned int pw[2][4][2];                // [blk][mt][half]
#pragma unroll
    for (int blk = 0; blk < 2; ++blk) {
      float ts = 0.f;
#pragma unroll
      for (int mt = 0; mt < 4; ++mt) {
        f32x4 p;
        for (int r = 0; r < 4; ++r) { p[r] = __expf(sc[blk][mt][r]); ts += p[r]; }
        sc[blk][mt] = p;
      }
      lsum[blk] += ts;
#pragma unroll
      for (int mt = 0; mt < 4; ++mt) {
        pw[blk][mt][0] = (unsigned int)f2bf(sc[blk][mt][0]) |
                         ((unsigned int)f2bf(sc[blk][mt][1]) << 16);
        pw[blk][mt][1] = (unsigned int)f2bf(sc[blk][mt][2]) |
                         ((unsigned int)f2bf(sc[blk][mt][3]) << 16);
      }
    }

    // PV with virtual key order (P-fragment straight from registers):
    // vk = q4*8+j -> key = kc2*32 + (j<4 ? q4*4+j : 16+q4*4+(j-4)); V read
    // with the same map; XOR chunk addressing (R22-verified expressions).
#pragma unroll
    for (int kc2 = 0; kc2 < 2; ++kc2) {
      u32x4 pa = {pw[0][2 * kc2][0], pw[0][2 * kc2][1],
                  pw[0][2 * kc2 + 1][0], pw[0][2 * kc2 + 1][1]};
      u32x4 pb = {pw[1][2 * kc2][0], pw[1][2 * kc2][1],
                  pw[1][2 * kc2 + 1][0], pw[1][2 * kc2 + 1][1]};
      bf16x8 pf0 = __builtin_bit_cast(bf16x8, pa);
      bf16x8 pf1 = __builtin_bit_cast(bf16x8, pb);
      const int clo = (4 * kc2 + (q4 >> 1)) ^ (c & 7);
      const int chi = (4 * kc2 + 2 + (q4 >> 1)) ^ (c & 7);
      const int sub = (q4 & 1) * 4;
      for (int nt = 0; nt < 8; ++nt) {
        const unsigned short* vrow = &VT[cur][(nt * 16 + c) * 64];
        u16x4 vlo = *(const u16x4*)(vrow + clo * 8 + sub);
        u16x4 vhi = *(const u16x4*)(vrow + chi * 8 + sub);
        bf16x8 vf = __builtin_bit_cast(bf16x8,
            __builtin_shufflevector(vlo, vhi, 0, 1, 2, 3, 4, 5, 6, 7));
        acc[0][nt] = __builtin_amdgcn_mfma_f32_16x16x32_bf16(pf0, vf, acc[0][nt], 0, 0, 0);
        acc[1][nt] = __builtin_amdgcn_mfma_f32_16x16x32_bf16(pf1, vf, acc[1][nt], 0, 0, 0);
      }
    }
    // no trailing barrier: next iter writes buf[cur^1]
  }

  unsigned short* ctxk = ctxp + (size_t)kb * SQ * HD;
  for (int blk = 0; blk < 2; ++blk) {
    float l = lsum[blk];
    l += __shfl_xor(l, 16);
    l += __shfl_xor(l, 32);
    float rl = 1.f / l;
    if (q4 == 0)
      lbuf[(size_t)kb * NHEADS * SQ + h * SQ + s0 + w * 32 + blk * 16 + c] = l;
    float r0 = __shfl(rl, q4 * 4 + 0);
    float r1 = __shfl(rl, q4 * 4 + 1);
    float r2 = __shfl(rl, q4 * 4 + 2);
    float r3 = __shfl(rl, q4 * 4 + 3);
    for (int nt = 0; nt < 8; ++nt) {
      int col = h * H + nt * 16 + c;
      int srow = s0 + w * 32 + blk * 16 + q4 * 4;
      ctxk[(size_t)(srow + 0) * HD + col] = f2bf(acc[blk][nt][0] * r0);
      ctxk[(size_t)(srow + 1) * HD + col] = f2bf(acc[blk][nt][1] * r1);
      ctxk[(size_t)(srow + 2) * HD + col] = f2bf(acc[blk][nt][2] * r2);
      ctxk[(size_t)(srow + 3) * HD + col] = f2bf(acc[blk][nt][3] * r3);
    }
  }
}

// ---------------- kernel 3: out = combine(ctxp) @ Wc + bc + x -------------
// grid 256 (16 rows/block): 4 waves split the 8 n-tiles (2 each, acc[2]).
__global__ __launch_bounds__(256) void out_kernel(
    const unsigned short* __restrict__ ctxp,
    const float* __restrict__ lbuf,
    const unsigned short* __restrict__ WcT,
    const float* __restrict__ bc,
    const float* __restrict__ x,
    float* __restrict__ out)
{
  __shared__ unsigned short At[16 * 136];
  __shared__ unsigned short Bt[128 * 136];
  const int tid = threadIdx.x;
  const int s0 = blockIdx.x * 16;
  const int lane = tid & 63, w = tid >> 6;
  const int c = lane & 15, q4 = lane >> 4;

  f32x4 acc[2];
  acc[0] = (f32x4){0.f, 0.f, 0.f, 0.f};
  acc[1] = (f32x4){0.f, 0.f, 0.f, 0.f};

  for (int kt = 0; kt < 8; ++kt) {         // head kt
    __syncthreads();
    {                                      // combine: one u16x8 per thread
      int row = tid >> 4, col8 = (tid & 15) * 8;
      const unsigned short* p0 = &ctxp[(size_t)(s0 + row) * HD + kt * 128 + col8];
      u16x8 a0 = *(const u16x8*)p0;
      u16x8 a1 = *(const u16x8*)(p0 + (size_t)SQ * HD);
      float la = lbuf[(size_t)kt * SQ + s0 + row];
      float lb = lbuf[(size_t)NHEADS * SQ + (size_t)kt * SQ + s0 + row];
      float ri = 1.f / (la + lb);
      float wa = la * ri, wb = lb * ri;
      u16x8 av;
      for (int e = 0; e < 8; ++e)
        av[e] = f2bf(wa * b2f(a0[e]) + wb * b2f(a1[e]));
      *(u16x8*)&At[row * 136 + col8] = av;
    }
    for (int i = 0; i < 8; ++i) {
      int ch = tid + i * 256;
      int row = ch >> 4, col8 = (ch & 15) * 8;
      *(u16x8*)&Bt[row * 136 + col8] =
          *(const u16x8*)&WcT[row * HD + kt * 128 + col8];
    }
    __syncthreads();
    bf16x8 af[4];
    for (int kc = 0; kc < 4; ++kc)
      af[kc] = ld_bf8(&At[c * 136 + kc * 32 + q4 * 8]);
    for (int j = 0; j < 2; ++j) {
      int nt = w * 2 + j;
      f32x4 a = acc[j];
      for (int kc = 0; kc < 4; ++kc) {
        bf16x8 bf = ld_bf8(&Bt[(nt * 16 + c) * 136 + kc * 32 + q4 * 8]);
        a = __builtin_amdgcn_mfma_f32_16x16x32_bf16(af[kc], bf, a, 0, 0, 0);
      }
      acc[j] = a;
    }
  }
  for (int j = 0; j < 2; ++j) {
    int nt = w * 2 + j;
    float bb = bc[nt * 16 + c];
    for (int r = 0; r < 4; ++r) {
      int srow = s0 + q4 * 4 + r;
      int col = nt * 16 + c;
      out[srow * H + col] = acc[j][r] + bb + x[srow * H + col];
    }
  }
}

extern "C" void kernel_launch(void* const* d_in, const int* in_sizes, int n_in,
                              void* d_out, int out_size, void* d_ws, size_t ws_size,
                              hipStream_t stream) {
  const float* x  = (const float*)d_in[0];
  const float* W1 = (const float*)d_in[1];
  const float* b1 = (const float*)d_in[2];
  const float* W2 = (const float*)d_in[3];
  const float* b2 = (const float*)d_in[4];
  const float* Wc = (const float*)d_in[5];
  const float* bc = (const float*)d_in[6];
  float* out = (float*)d_out;

  // Key-split layout (42,991,616 B) -- R10's proven 2-way layout.
  char* ws = (char*)d_ws;
  unsigned short* q1bf = (unsigned short*)ws; ws += (size_t)NHEADS * SQ * H * 2;
  unsigned short* q2K  = (unsigned short*)ws; ws += (size_t)NHEADS * SQ * H * 2;
  unsigned short* q2VT = (unsigned short*)ws; ws += (size_t)NHEADS * SQ * H * 2;
  unsigned short* ctxp = (unsigned short*)ws; ws += (size_t)2 * SQ * HD * 2;
  float*          lbuf = (float*)ws;          ws += (size_t)2 * NHEADS * SQ * 4;
  unsigned short* W1T  = (unsigned short*)ws; ws += (size_t)HD * H * 2;
  unsigned short* W2T  = (unsigned short*)ws; ws += (size_t)HD * H * 2;
  unsigned short* WcT  = (unsigned short*)ws; ws += (size_t)HD * H * 2;

  prep_kernel<<<64, 256, 0, stream>>>(W1, W2, Wc, W1T, W2T, WcT);
  proj_kernel<<<512, 256, 0, stream>>>(x, b1, b2, W1T, W2T, q1bf, q2K, q2VT);
  flash_kernel<<<512, 256, 0, stream>>>(q1bf, q2K, q2VT, ctxp, lbuf);
  out_kernel<<<256, 256, 0, stream>>>(ctxp, lbuf, WcT, bc, x, out);
}

// Round 18
// 169.699 us; speedup vs baseline: 1.0594x; 1.0594x over previous
//
#include <hip/hip_runtime.h>

#define H 128
#define NHEADS 8
#define SQ 4096
#define HD 1024   // NHEADS*H

typedef float f32x4 __attribute__((ext_vector_type(4)));
typedef __bf16 bf16x8 __attribute__((ext_vector_type(8)));
typedef unsigned short u16x4 __attribute__((ext_vector_type(4)));
typedef unsigned short u16x8 __attribute__((ext_vector_type(8)));
typedef unsigned int u32x4 __attribute__((ext_vector_type(4)));

static __device__ __forceinline__ unsigned short f2bf(float f) {
  unsigned int u = __builtin_bit_cast(unsigned int, f);
  u += 0x7fffu + ((u >> 16) & 1u);           // round-nearest-even
  return (unsigned short)(u >> 16);
}
static __device__ __forceinline__ float b2f(unsigned short s) {
  unsigned int u = (unsigned int)s << 16;
  return __builtin_bit_cast(float, u);
}
static __device__ __forceinline__ bf16x8 ld_bf8(const unsigned short* p) {
  return __builtin_bit_cast(bf16x8, *(const u16x8*)p);
}

// ---------------- kernel 0: weight transpose+convert, LDS-tiled -----------
// grid 64. Blocks 0..31: W1+W2; 32..63: Wc. 64x64 tiles; pitch 66 (scalar
// 2B accesses only -- the b128 16-byte-alignment rule does not apply here).
__global__ __launch_bounds__(256) void prep_kernel(
    const float* __restrict__ W1, const float* __restrict__ W2,
    const float* __restrict__ Wc,
    unsigned short* __restrict__ W1T, unsigned short* __restrict__ W2T,
    unsigned short* __restrict__ WcT)
{
  __shared__ unsigned short tile[64 * 66];
  const int b = blockIdx.x, tid = threadIdx.x;
  if (b < 32) {
    const int k0 = (b & 1) * 64, n0 = (b >> 1) * 64;
    for (int i = 0; i < 16; ++i) {
      int idx = tid + i * 256;
      int r = idx >> 6, cc = idx & 63;       // r = k-local, cc = n-local
      tile[cc * 66 + r] = f2bf(W1[(size_t)(k0 + r) * HD + n0 + cc]);
    }
    __syncthreads();
    for (int i = 0; i < 16; ++i) {
      int idx = tid + i * 256;
      int r = idx >> 6, cc = idx & 63;       // r = n-local, cc = k-local
      W1T[(size_t)(n0 + r) * H + k0 + cc] = tile[r * 66 + cc];
    }
    __syncthreads();
    for (int i = 0; i < 16; ++i) {
      int idx = tid + i * 256;
      int r = idx >> 6, cc = idx & 63;
      tile[cc * 66 + r] = f2bf(W2[(size_t)(k0 + r) * HD + n0 + cc]);
    }
    __syncthreads();
    for (int i = 0; i < 16; ++i) {
      int idx = tid + i * 256;
      int r = idx >> 6, cc = idx & 63;
      W2T[(size_t)(n0 + r) * H + k0 + cc] = tile[r * 66 + cc];
    }
  } else {
    const int bb = b - 32;
    const int n0 = (bb & 1) * 64, k0 = (bb >> 1) * 64;
    for (int i = 0; i < 16; ++i) {
      int idx = tid + i * 256;
      int r = idx >> 6, cc = idx & 63;       // r = k-local, cc = n-local
      tile[cc * 66 + r] = f2bf(Wc[(size_t)(k0 + r) * H + n0 + cc]);
    }
    __syncthreads();
    for (int i = 0; i < 16; ++i) {
      int idx = tid + i * 256;
      int r = idx >> 6, cc = idx & 63;       // r = n-local, cc = k-local
      WcT[(size_t)(n0 + r) * HD + k0 + cc] = tile[r * 66 + cc];
    }
  }
}

// ---------------- kernel 1: q1/q2 projection, coalesced stores ------------
__global__ __launch_bounds__(256) void proj_kernel(
    const float* __restrict__ x,
    const float* __restrict__ b1, const float* __restrict__ b2,
    const unsigned short* __restrict__ W1T, const unsigned short* __restrict__ W2T,
    unsigned short* __restrict__ q1bf, unsigned short* __restrict__ q2K,
    unsigned short* __restrict__ q2VT)
{
  __shared__ unsigned short At[64 * 136];
  __shared__ unsigned short Bt[128 * 136];
  const int tid = threadIdx.x;
  const int st = blockIdx.x & 63, h = blockIdx.x >> 6;
  const int s0 = st * 64;
  const int lane = tid & 63, w = tid >> 6;
  const int c = lane & 15, q4 = lane >> 4;

  for (int i = 0; i < 4; ++i) {
    int ch = tid + i * 256;
    int row = ch >> 4, col8 = (ch & 15) * 8;
    const float* gp = x + (s0 + row) * H + col8;
    f32x4 a = *(const f32x4*)gp;
    f32x4 b = *(const f32x4*)(gp + 4);
    u16x8 v;
    v[0]=f2bf(a[0]); v[1]=f2bf(a[1]); v[2]=f2bf(a[2]); v[3]=f2bf(a[3]);
    v[4]=f2bf(b[0]); v[5]=f2bf(b[1]); v[6]=f2bf(b[2]); v[7]=f2bf(b[3]);
    *(u16x8*)&At[row * 136 + col8] = v;
  }
  for (int i = 0; i < 8; ++i) {
    int ch = tid + i * 256;
    int row = ch >> 4, col8 = (ch & 15) * 8;
    *(u16x8*)&Bt[row * 136 + col8] = *(const u16x8*)&W1T[(h * H + row) * H + col8];
  }
  __syncthreads();                           // S1

  bf16x8 af[4];                              // A-frags (reused for q1 and q2)
  for (int kc = 0; kc < 4; ++kc)
    af[kc] = ld_bf8(&At[(w * 16 + c) * 136 + kc * 32 + q4 * 8]);
  __syncthreads();                           // S2: all af hoisted; At reusable

  // q1 = x @ W1 + b1 -> stage into At as [s-local][d]
  for (int nt = 0; nt < 8; ++nt) {
    f32x4 acc = {0.f, 0.f, 0.f, 0.f};
    for (int kc = 0; kc < 4; ++kc) {
      bf16x8 bf = ld_bf8(&Bt[(nt * 16 + c) * 136 + kc * 32 + q4 * 8]);
      acc = __builtin_amdgcn_mfma_f32_16x16x32_bf16(af[kc], bf, acc, 0, 0, 0);
    }
    float bb = b1[h * H + nt * 16 + c];
    for (int r = 0; r < 4; ++r)
      At[(w * 16 + q4 * 4 + r) * 136 + nt * 16 + c] = f2bf(acc[r] + bb);
  }
  __syncthreads();                           // S3

  for (int i = 0; i < 4; ++i) {
    int ch = tid + i * 256;
    int row = ch >> 4, col8 = (ch & 15) * 8;
    *(u16x8*)&q1bf[(size_t)(h * SQ + s0 + row) * H + col8] =
        *(const u16x8*)&At[row * 136 + col8];
  }
  for (int i = 0; i < 8; ++i) {
    int ch = tid + i * 256;
    int row = ch >> 4, col8 = (ch & 15) * 8;
    *(u16x8*)&Bt[row * 136 + col8] = *(const u16x8*)&W2T[(h * H + row) * H + col8];
  }
  __syncthreads();                           // S4

  f32x4 q2a[8];
  for (int nt = 0; nt < 8; ++nt) {
    f32x4 acc = {0.f, 0.f, 0.f, 0.f};
    for (int kc = 0; kc < 4; ++kc) {
      bf16x8 bf = ld_bf8(&Bt[(nt * 16 + c) * 136 + kc * 32 + q4 * 8]);
      acc = __builtin_amdgcn_mfma_f32_16x16x32_bf16(af[kc], bf, acc, 0, 0, 0);
    }
    q2a[nt] = acc;
  }
  __syncthreads();                           // S5

  for (int nt = 0; nt < 8; ++nt) {
    float bb = b2[h * H + nt * 16 + c];
    unsigned short vs[4];
    for (int r = 0; r < 4; ++r) {
      unsigned short u = f2bf(q2a[nt][r] + bb);
      At[(w * 16 + q4 * 4 + r) * 136 + nt * 16 + c] = u;
      vs[r] = u;
    }
    u16x4 v4 = {vs[0], vs[1], vs[2], vs[3]};
    *(u16x4*)&Bt[(nt * 16 + c) * 72 + w * 16 + q4 * 4] = v4;
  }
  __syncthreads();                           // S6

  for (int i = 0; i < 4; ++i) {
    int ch = tid + i * 256;
    int row = ch >> 4, col8 = (ch & 15) * 8;
    *(u16x8*)&q2K[(size_t)(h * SQ + s0 + row) * H + col8] =
        *(const u16x8*)&At[row * 136 + col8];
  }
  for (int i = 0; i < 4; ++i) {
    int ch = tid + i * 256;
    int row = ch >> 3, col8 = (ch & 7) * 8;  // row = d 0..127
    *(u16x8*)&q2VT[(size_t)(h * H + row) * SQ + s0 + col8] =
        *(const u16x8*)&Bt[row * 72 + col8];
  }
}

// ---------------- kernel 2: flash attention, 2-way KEY-SPLIT --------------
// R28 = R25 champion verbatim (168.4 us total; flash 94.0 us). Complete
// ledger of bounded levers (13 probing rounds):
//  - Pb LDS round trip: removed via kappa key-permutation (R18, +0.7).
//  - barrier halving via LDS double-buffer (R25, +2.7): 1 barrier/kt.
//  - occupancy >2 blocks/CU: never co-schedules at these LDS sizes (R19).
//  - global-K instead of LDS: vmem saturates + exposed latency (R12).
//  - global_load_lds DMA staging: vmcnt(0)-at-barrier drains worse than
//    reg-staging's dependency-based early drain (R27: 94->102).
//  - deeper q-amortization: register/grid frontier (R11/R13/R14).
//  - LDS pitch: b128 requires 8-short multiples (R20); 68/36-dw pitches
//    are in the proven bank class (stride = 4 mod 32 dw).
//  - SQ_LDS_BANK_CONFLICT 1.258e7 invariant across layouts (R18/R19/R22/
//    R25) -> benign wave64 2-way aliasing, not a cost.
//  - P-pack must be RNE-exact f2bf (R16/R17/R23 all failed numerics).
// Flash = verified multi-pipe local optimum of this decomposition.
__global__ __launch_bounds__(256, 2) void flash_kernel(
    const unsigned short* __restrict__ q1bf,
    const unsigned short* __restrict__ q2K,
    const unsigned short* __restrict__ q2VT,
    unsigned short* __restrict__ ctxp,   // [kb][s][h*128+d] bf16, local-normed
    float* __restrict__ lbuf)            // [kb][h][s]
{
  __shared__ unsigned short Kt[2][64 * 136];   // [key][d]  pitch 136 (68 dw)
  __shared__ unsigned short VT[2][128 * 72];   // [d][key]  pitch 72  (36 dw)
  const int tid = threadIdx.x;
  const int bid = blockIdx.x;
  const int kb = bid >> 8;                     // key half
  const int h = (bid >> 5) & 7, qb = bid & 31;
  const int s0 = qb * 128;
  const int kbase = kb * 2048;                 // 32 tiles each
  const int lane = tid & 63, w = tid >> 6;
  const int c = lane & 15, q4 = lane >> 4;

  bf16x8 qf[2][4];
  for (int blk = 0; blk < 2; ++blk)
    for (int kc = 0; kc < 4; ++kc)
      qf[blk][kc] = ld_bf8(
          &q1bf[(h * SQ + s0 + w * 32 + blk * 16 + c) * H + kc * 32 + q4 * 8]);

  f32x4 acc[2][8];
  for (int blk = 0; blk < 2; ++blk)
    for (int nt = 0; nt < 8; ++nt) acc[blk][nt] = (f32x4){0.f, 0.f, 0.f, 0.f};
  float lsum[2] = {0.f, 0.f};

  u16x8 kreg[4], vreg[4];
  for (int i = 0; i < 4; ++i) {
    int ch = tid + i * 256;
    kreg[i] = *(const u16x8*)&q2K[(h * SQ + kbase + (ch >> 4)) * H + (ch & 15) * 8];
    vreg[i] = *(const u16x8*)&q2VT[(h * H + (ch >> 3)) * SQ + kbase + (ch & 7) * 8];
  }

  for (int kt = 0; kt < 32; ++kt) {
    const int cur = kt & 1;
    // write this tile into buf[cur]; prior reads were from buf[cur^1],
    // protected by the single barrier below.
    for (int i = 0; i < 4; ++i) {
      int ch = tid + i * 256;
      *(u16x8*)&Kt[cur][(ch >> 4) * 136 + (ch & 15) * 8] = kreg[i];
      *(u16x8*)&VT[cur][(ch >> 3) * 72 + (ch & 7) * 8] = vreg[i];
    }
    __syncthreads();                         // buf[cur] ready

    if (kt < 31) {                           // K/V prefetch for kt+1
      const int k0 = kbase + (kt + 1) * 64;
      for (int i = 0; i < 4; ++i) {
        int ch = tid + i * 256;
        kreg[i] = *(const u16x8*)&q2K[(h * SQ + k0 + (ch >> 4)) * H + (ch & 15) * 8];
        vreg[i] = *(const u16x8*)&q2VT[(h * H + (ch >> 3)) * SQ + k0 + (ch & 7) * 8];
      }
    }

    f32x4 sc[2][4];
    for (int mt = 0; mt < 4; ++mt) {
      bf16x8 kf[4];
      for (int kc = 0; kc < 4; ++kc)
        kf[kc] = ld_bf8(&Kt[cur][(mt * 16 + c) * 136 + kc * 32 + q4 * 8]);
      for (int blk = 0; blk < 2; ++blk) {
        f32x4 s = {0.f, 0.f, 0.f, 0.f};
        for (int kc = 0; kc < 4; ++kc)
          s = __builtin_amdgcn_mfma_f32_16x16x32_bf16(kf[kc], qf[blk][kc], s, 0, 0, 0);
        sc[blk][mt] = s;
      }
    }

    // softmax + plain-C bf16 pack (f2bf == the proven Pb path's rounding)
    unsigned int pw[2][4][2];                // [blk][mt][half]
#pragma unroll
    for (int blk = 0; blk < 2; ++blk) {
      float ts = 0.f;
#pragma unroll
      for (int mt = 0; mt < 4; ++mt) {
        f32x4 p;
        for (int r = 0; r < 4; ++r) { p[r] = __expf(sc[blk][mt][r]); ts += p[r]; }
        sc[blk][mt] = p;
      }
      lsum[blk] += ts;
#pragma unroll
      for (int mt = 0; mt < 4; ++mt) {
        pw[blk][mt][0] = (unsigned int)f2bf(sc[blk][mt][0]) |
                         ((unsigned int)f2bf(sc[blk][mt][1]) << 16);
        pw[blk][mt][1] = (unsigned int)f2bf(sc[blk][mt][2]) |
                         ((unsigned int)f2bf(sc[blk][mt][3]) << 16);
      }
    }

    // PV with virtual key order (P-fragment straight from registers):
    // vk = q4*8+j -> key = kc2*32 + (j<4 ? q4*4+j : 16+q4*4+(j-4)); V read
    // with the same map (two b64 at +0 / +16 shorts) -> key-sum exact.
#pragma unroll
    for (int kc2 = 0; kc2 < 2; ++kc2) {
      u32x4 pa = {pw[0][2 * kc2][0], pw[0][2 * kc2][1],
                  pw[0][2 * kc2 + 1][0], pw[0][2 * kc2 + 1][1]};
      u32x4 pb = {pw[1][2 * kc2][0], pw[1][2 * kc2][1],
                  pw[1][2 * kc2 + 1][0], pw[1][2 * kc2 + 1][1]};
      bf16x8 pf0 = __builtin_bit_cast(bf16x8, pa);
      bf16x8 pf1 = __builtin_bit_cast(bf16x8, pb);
      for (int nt = 0; nt < 8; ++nt) {
        const unsigned short* vp = &VT[cur][(nt * 16 + c) * 72 + kc2 * 32 + q4 * 4];
        u16x4 vlo = *(const u16x4*)vp;         // keys kc2*32 + q4*4 + 0..3
        u16x4 vhi = *(const u16x4*)(vp + 16);  // keys kc2*32 + 16 + q4*4 + 0..3
        bf16x8 vf = __builtin_bit_cast(bf16x8,
            __builtin_shufflevector(vlo, vhi, 0, 1, 2, 3, 4, 5, 6, 7));
        acc[0][nt] = __builtin_amdgcn_mfma_f32_16x16x32_bf16(pf0, vf, acc[0][nt], 0, 0, 0);
        acc[1][nt] = __builtin_amdgcn_mfma_f32_16x16x32_bf16(pf1, vf, acc[1][nt], 0, 0, 0);
      }
    }
    // no trailing barrier: next iter writes buf[cur^1]
  }

  unsigned short* ctxk = ctxp + (size_t)kb * SQ * HD;
  for (int blk = 0; blk < 2; ++blk) {
    float l = lsum[blk];
    l += __shfl_xor(l, 16);
    l += __shfl_xor(l, 32);
    float rl = 1.f / l;
    if (q4 == 0)
      lbuf[(size_t)kb * NHEADS * SQ + h * SQ + s0 + w * 32 + blk * 16 + c] = l;
    float r0 = __shfl(rl, q4 * 4 + 0);
    float r1 = __shfl(rl, q4 * 4 + 1);
    float r2 = __shfl(rl, q4 * 4 + 2);
    float r3 = __shfl(rl, q4 * 4 + 3);
    for (int nt = 0; nt < 8; ++nt) {
      int col = h * H + nt * 16 + c;
      int srow = s0 + w * 32 + blk * 16 + q4 * 4;
      ctxk[(size_t)(srow + 0) * HD + col] = f2bf(acc[blk][nt][0] * r0);
      ctxk[(size_t)(srow + 1) * HD + col] = f2bf(acc[blk][nt][1] * r1);
      ctxk[(size_t)(srow + 2) * HD + col] = f2bf(acc[blk][nt][2] * r2);
      ctxk[(size_t)(srow + 3) * HD + col] = f2bf(acc[blk][nt][3] * r3);
    }
  }
}

// ---------------- kernel 3: out = combine(ctxp) @ Wc + bc + x -------------
// grid 256 (16 rows/block): 4 waves split the 8 n-tiles (2 each, acc[2]).
__global__ __launch_bounds__(256) void out_kernel(
    const unsigned short* __restrict__ ctxp,
    const float* __restrict__ lbuf,
    const unsigned short* __restrict__ WcT,
    const float* __restrict__ bc,
    const float* __restrict__ x,
    float* __restrict__ out)
{
  __shared__ unsigned short At[16 * 136];
  __shared__ unsigned short Bt[128 * 136];
  const int tid = threadIdx.x;
  const int s0 = blockIdx.x * 16;
  const int lane = tid & 63, w = tid >> 6;
  const int c = lane & 15, q4 = lane >> 4;

  f32x4 acc[2];
  acc[0] = (f32x4){0.f, 0.f, 0.f, 0.f};
  acc[1] = (f32x4){0.f, 0.f, 0.f, 0.f};

  for (int kt = 0; kt < 8; ++kt) {         // head kt
    __syncthreads();
    {                                      // combine: one u16x8 per thread
      int row = tid >> 4, col8 = (tid & 15) * 8;
      const unsigned short* p0 = &ctxp[(size_t)(s0 + row) * HD + kt * 128 + col8];
      u16x8 a0 = *(const u16x8*)p0;
      u16x8 a1 = *(const u16x8*)(p0 + (size_t)SQ * HD);
      float la = lbuf[(size_t)kt * SQ + s0 + row];
      float lb = lbuf[(size_t)NHEADS * SQ + (size_t)kt * SQ + s0 + row];
      float ri = 1.f / (la + lb);
      float wa = la * ri, wb = lb * ri;
      u16x8 av;
      for (int e = 0; e < 8; ++e)
        av[e] = f2bf(wa * b2f(a0[e]) + wb * b2f(a1[e]));
      *(u16x8*)&At[row * 136 + col8] = av;
    }
    for (int i = 0; i < 8; ++i) {
      int ch = tid + i * 256;
      int row = ch >> 4, col8 = (ch & 15) * 8;
      *(u16x8*)&Bt[row * 136 + col8] =
          *(const u16x8*)&WcT[row * HD + kt * 128 + col8];
    }
    __syncthreads();
    bf16x8 af[4];
    for (int kc = 0; kc < 4; ++kc)
      af[kc] = ld_bf8(&At[c * 136 + kc * 32 + q4 * 8]);
    for (int j = 0; j < 2; ++j) {
      int nt = w * 2 + j;
      f32x4 a = acc[j];
      for (int kc = 0; kc < 4; ++kc) {
        bf16x8 bf = ld_bf8(&Bt[(nt * 16 + c) * 136 + kc * 32 + q4 * 8]);
        a = __builtin_amdgcn_mfma_f32_16x16x32_bf16(af[kc], bf, a, 0, 0, 0);
      }
      acc[j] = a;
    }
  }
  for (int j = 0; j < 2; ++j) {
    int nt = w * 2 + j;
    float bb = bc[nt * 16 + c];
    for (int r = 0; r < 4; ++r) {
      int srow = s0 + q4 * 4 + r;
      int col = nt * 16 + c;
      out[srow * H + col] = acc[j][r] + bb + x[srow * H + col];
    }
  }
}

extern "C" void kernel_launch(void* const* d_in, const int* in_sizes, int n_in,
                              void* d_out, int out_size, void* d_ws, size_t ws_size,
                              hipStream_t stream) {
  const float* x  = (const float*)d_in[0];
  const float* W1 = (const float*)d_in[1];
  const float* b1 = (const float*)d_in[2];
  const float* W2 = (const float*)d_in[3];
  const float* b2 = (const float*)d_in[4];
  const float* Wc = (const float*)d_in[5];
  const float* bc = (const float*)d_in[6];
  float* out = (float*)d_out;

  // Key-split layout (42,991,616 B) -- R10's proven 2-way layout.
  char* ws = (char*)d_ws;
  unsigned short* q1bf = (unsigned short*)ws; ws += (size_t)NHEADS * SQ * H * 2;
  unsigned short* q2K  = (unsigned short*)ws; ws += (size_t)NHEADS * SQ * H * 2;
  unsigned short* q2VT = (unsigned short*)ws; ws += (size_t)NHEADS * SQ * H * 2;
  unsigned short* ctxp = (unsigned short*)ws; ws += (size_t)2 * SQ * HD * 2;
  float*          lbuf = (float*)ws;          ws += (size_t)2 * NHEADS * SQ * 4;
  unsigned short* W1T  = (unsigned short*)ws; ws += (size_t)HD * H * 2;
  unsigned short* W2T  = (unsigned short*)ws; ws += (size_t)HD * H * 2;
  unsigned short* WcT  = (unsigned short*)ws; ws += (size_t)HD * H * 2;

  prep_kernel<<<64, 256, 0, stream>>>(W1, W2, Wc, W1T, W2T, WcT);
  proj_kernel<<<512, 256, 0, stream>>>(x, b1, b2, W1T, W2T, q1bf, q2K, q2VT);
  flash_kernel<<<512, 256, 0, stream>>>(q1bf, q2K, q2VT, ctxp, lbuf);
  out_kernel<<<256, 256, 0, stream>>>(ctxp, lbuf, WcT, bc, x, out);
}

// Round 19
// 166.593 us; speedup vs baseline: 1.0791x; 1.0186x over previous
//
#include <hip/hip_runtime.h>

#define H 128
#define NHEADS 8
#define SQ 4096
#define HD 1024   // NHEADS*H

typedef float f32x4 __attribute__((ext_vector_type(4)));
typedef __bf16 bf16x8 __attribute__((ext_vector_type(8)));
typedef unsigned short u16x4 __attribute__((ext_vector_type(4)));
typedef unsigned short u16x8 __attribute__((ext_vector_type(8)));
typedef unsigned int u32x4 __attribute__((ext_vector_type(4)));

static __device__ __forceinline__ unsigned short f2bf(float f) {
  unsigned int u = __builtin_bit_cast(unsigned int, f);
  u += 0x7fffu + ((u >> 16) & 1u);           // round-nearest-even
  return (unsigned short)(u >> 16);
}
static __device__ __forceinline__ float b2f(unsigned short s) {
  unsigned int u = (unsigned int)s << 16;
  return __builtin_bit_cast(float, u);
}
static __device__ __forceinline__ bf16x8 ld_bf8(const unsigned short* p) {
  return __builtin_bit_cast(bf16x8, *(const u16x8*)p);
}

// ---------------- kernel 0: weight transpose+convert, LDS-tiled -----------
// grid 64. Blocks 0..31: W1+W2; 32..63: Wc. 64x64 tiles; pitch 66 (scalar
// 2B accesses only -- the b128 16-byte-alignment rule does not apply here).
__global__ __launch_bounds__(256) void prep_kernel(
    const float* __restrict__ W1, const float* __restrict__ W2,
    const float* __restrict__ Wc,
    unsigned short* __restrict__ W1T, unsigned short* __restrict__ W2T,
    unsigned short* __restrict__ WcT)
{
  __shared__ unsigned short tile[64 * 66];
  const int b = blockIdx.x, tid = threadIdx.x;
  if (b < 32) {
    const int k0 = (b & 1) * 64, n0 = (b >> 1) * 64;
    for (int i = 0; i < 16; ++i) {
      int idx = tid + i * 256;
      int r = idx >> 6, cc = idx & 63;       // r = k-local, cc = n-local
      tile[cc * 66 + r] = f2bf(W1[(size_t)(k0 + r) * HD + n0 + cc]);
    }
    __syncthreads();
    for (int i = 0; i < 16; ++i) {
      int idx = tid + i * 256;
      int r = idx >> 6, cc = idx & 63;       // r = n-local, cc = k-local
      W1T[(size_t)(n0 + r) * H + k0 + cc] = tile[r * 66 + cc];
    }
    __syncthreads();
    for (int i = 0; i < 16; ++i) {
      int idx = tid + i * 256;
      int r = idx >> 6, cc = idx & 63;
      tile[cc * 66 + r] = f2bf(W2[(size_t)(k0 + r) * HD + n0 + cc]);
    }
    __syncthreads();
    for (int i = 0; i < 16; ++i) {
      int idx = tid + i * 256;
      int r = idx >> 6, cc = idx & 63;
      W2T[(size_t)(n0 + r) * H + k0 + cc] = tile[r * 66 + cc];
    }
  } else {
    const int bb = b - 32;
    const int n0 = (bb & 1) * 64, k0 = (bb >> 1) * 64;
    for (int i = 0; i < 16; ++i) {
      int idx = tid + i * 256;
      int r = idx >> 6, cc = idx & 63;       // r = k-local, cc = n-local
      tile[cc * 66 + r] = f2bf(Wc[(size_t)(k0 + r) * H + n0 + cc]);
    }
    __syncthreads();
    for (int i = 0; i < 16; ++i) {
      int idx = tid + i * 256;
      int r = idx >> 6, cc = idx & 63;       // r = n-local, cc = k-local
      WcT[(size_t)(n0 + r) * HD + k0 + cc] = tile[r * 66 + cc];
    }
  }
}

// ---------------- kernel 1: q1/q2 projection, coalesced stores ------------
__global__ __launch_bounds__(256) void proj_kernel(
    const float* __restrict__ x,
    const float* __restrict__ b1, const float* __restrict__ b2,
    const unsigned short* __restrict__ W1T, const unsigned short* __restrict__ W2T,
    unsigned short* __restrict__ q1bf, unsigned short* __restrict__ q2K,
    unsigned short* __restrict__ q2VT)
{
  __shared__ unsigned short At[64 * 136];
  __shared__ unsigned short Bt[128 * 136];
  const int tid = threadIdx.x;
  const int st = blockIdx.x & 63, h = blockIdx.x >> 6;
  const int s0 = st * 64;
  const int lane = tid & 63, w = tid >> 6;
  const int c = lane & 15, q4 = lane >> 4;

  for (int i = 0; i < 4; ++i) {
    int ch = tid + i * 256;
    int row = ch >> 4, col8 = (ch & 15) * 8;
    const float* gp = x + (s0 + row) * H + col8;
    f32x4 a = *(const f32x4*)gp;
    f32x4 b = *(const f32x4*)(gp + 4);
    u16x8 v;
    v[0]=f2bf(a[0]); v[1]=f2bf(a[1]); v[2]=f2bf(a[2]); v[3]=f2bf(a[3]);
    v[4]=f2bf(b[0]); v[5]=f2bf(b[1]); v[6]=f2bf(b[2]); v[7]=f2bf(b[3]);
    *(u16x8*)&At[row * 136 + col8] = v;
  }
  for (int i = 0; i < 8; ++i) {
    int ch = tid + i * 256;
    int row = ch >> 4, col8 = (ch & 15) * 8;
    *(u16x8*)&Bt[row * 136 + col8] = *(const u16x8*)&W1T[(h * H + row) * H + col8];
  }
  __syncthreads();                           // S1

  bf16x8 af[4];                              // A-frags (reused for q1 and q2)
  for (int kc = 0; kc < 4; ++kc)
    af[kc] = ld_bf8(&At[(w * 16 + c) * 136 + kc * 32 + q4 * 8]);
  __syncthreads();                           // S2: all af hoisted; At reusable

  // q1 = x @ W1 + b1 -> stage into At as [s-local][d]
  for (int nt = 0; nt < 8; ++nt) {
    f32x4 acc = {0.f, 0.f, 0.f, 0.f};
    for (int kc = 0; kc < 4; ++kc) {
      bf16x8 bf = ld_bf8(&Bt[(nt * 16 + c) * 136 + kc * 32 + q4 * 8]);
      acc = __builtin_amdgcn_mfma_f32_16x16x32_bf16(af[kc], bf, acc, 0, 0, 0);
    }
    float bb = b1[h * H + nt * 16 + c];
    for (int r = 0; r < 4; ++r)
      At[(w * 16 + q4 * 4 + r) * 136 + nt * 16 + c] = f2bf(acc[r] + bb);
  }
  __syncthreads();                           // S3

  for (int i = 0; i < 4; ++i) {
    int ch = tid + i * 256;
    int row = ch >> 4, col8 = (ch & 15) * 8;
    *(u16x8*)&q1bf[(size_t)(h * SQ + s0 + row) * H + col8] =
        *(const u16x8*)&At[row * 136 + col8];
  }
  for (int i = 0; i < 8; ++i) {
    int ch = tid + i * 256;
    int row = ch >> 4, col8 = (ch & 15) * 8;
    *(u16x8*)&Bt[row * 136 + col8] = *(const u16x8*)&W2T[(h * H + row) * H + col8];
  }
  __syncthreads();                           // S4

  f32x4 q2a[8];
  for (int nt = 0; nt < 8; ++nt) {
    f32x4 acc = {0.f, 0.f, 0.f, 0.f};
    for (int kc = 0; kc < 4; ++kc) {
      bf16x8 bf = ld_bf8(&Bt[(nt * 16 + c) * 136 + kc * 32 + q4 * 8]);
      acc = __builtin_amdgcn_mfma_f32_16x16x32_bf16(af[kc], bf, acc, 0, 0, 0);
    }
    q2a[nt] = acc;
  }
  __syncthreads();                           // S5

  for (int nt = 0; nt < 8; ++nt) {
    float bb = b2[h * H + nt * 16 + c];
    unsigned short vs[4];
    for (int r = 0; r < 4; ++r) {
      unsigned short u = f2bf(q2a[nt][r] + bb);
      At[(w * 16 + q4 * 4 + r) * 136 + nt * 16 + c] = u;
      vs[r] = u;
    }
    u16x4 v4 = {vs[0], vs[1], vs[2], vs[3]};
    *(u16x4*)&Bt[(nt * 16 + c) * 72 + w * 16 + q4 * 4] = v4;
  }
  __syncthreads();                           // S6

  for (int i = 0; i < 4; ++i) {
    int ch = tid + i * 256;
    int row = ch >> 4, col8 = (ch & 15) * 8;
    *(u16x8*)&q2K[(size_t)(h * SQ + s0 + row) * H + col8] =
        *(const u16x8*)&At[row * 136 + col8];
  }
  for (int i = 0; i < 4; ++i) {
    int ch = tid + i * 256;
    int row = ch >> 3, col8 = (ch & 7) * 8;  // row = d 0..127
    *(u16x8*)&q2VT[(size_t)(h * H + row) * SQ + s0 + col8] =
        *(const u16x8*)&Bt[row * 72 + col8];
  }
}

// ---------------- kernel 2: flash attention, 2-way KEY-SPLIT --------------
// R29 = R25/R28 champion + s_setprio(1) around the two MFMA clusters (T5).
// Mechanism (m191): 2 independent blocks/CU at different phases -> the
// MFMA-phase wave wins issue arbitration over staging/softmax waves.
// Pure scheduler hint: no layout/sync/numerics change. m190's null was
// barrier-lockstep GEMM; our blocks are unsynchronized like m191's attn.
__global__ __launch_bounds__(256, 2) void flash_kernel(
    const unsigned short* __restrict__ q1bf,
    const unsigned short* __restrict__ q2K,
    const unsigned short* __restrict__ q2VT,
    unsigned short* __restrict__ ctxp,   // [kb][s][h*128+d] bf16, local-normed
    float* __restrict__ lbuf)            // [kb][h][s]
{
  __shared__ unsigned short Kt[2][64 * 136];   // [key][d]  pitch 136 (68 dw)
  __shared__ unsigned short VT[2][128 * 72];   // [d][key]  pitch 72  (36 dw)
  const int tid = threadIdx.x;
  const int bid = blockIdx.x;
  const int kb = bid >> 8;                     // key half
  const int h = (bid >> 5) & 7, qb = bid & 31;
  const int s0 = qb * 128;
  const int kbase = kb * 2048;                 // 32 tiles each
  const int lane = tid & 63, w = tid >> 6;
  const int c = lane & 15, q4 = lane >> 4;

  bf16x8 qf[2][4];
  for (int blk = 0; blk < 2; ++blk)
    for (int kc = 0; kc < 4; ++kc)
      qf[blk][kc] = ld_bf8(
          &q1bf[(h * SQ + s0 + w * 32 + blk * 16 + c) * H + kc * 32 + q4 * 8]);

  f32x4 acc[2][8];
  for (int blk = 0; blk < 2; ++blk)
    for (int nt = 0; nt < 8; ++nt) acc[blk][nt] = (f32x4){0.f, 0.f, 0.f, 0.f};
  float lsum[2] = {0.f, 0.f};

  u16x8 kreg[4], vreg[4];
  for (int i = 0; i < 4; ++i) {
    int ch = tid + i * 256;
    kreg[i] = *(const u16x8*)&q2K[(h * SQ + kbase + (ch >> 4)) * H + (ch & 15) * 8];
    vreg[i] = *(const u16x8*)&q2VT[(h * H + (ch >> 3)) * SQ + kbase + (ch & 7) * 8];
  }

  for (int kt = 0; kt < 32; ++kt) {
    const int cur = kt & 1;
    // write this tile into buf[cur]; prior reads were from buf[cur^1],
    // protected by the single barrier below.
    for (int i = 0; i < 4; ++i) {
      int ch = tid + i * 256;
      *(u16x8*)&Kt[cur][(ch >> 4) * 136 + (ch & 15) * 8] = kreg[i];
      *(u16x8*)&VT[cur][(ch >> 3) * 72 + (ch & 7) * 8] = vreg[i];
    }
    __syncthreads();                         // buf[cur] ready

    if (kt < 31) {                           // K/V prefetch for kt+1
      const int k0 = kbase + (kt + 1) * 64;
      for (int i = 0; i < 4; ++i) {
        int ch = tid + i * 256;
        kreg[i] = *(const u16x8*)&q2K[(h * SQ + k0 + (ch >> 4)) * H + (ch & 15) * 8];
        vreg[i] = *(const u16x8*)&q2VT[(h * H + (ch >> 3)) * SQ + k0 + (ch & 7) * 8];
      }
    }

    // QK^T MFMA cluster (priority-boosted)
    __builtin_amdgcn_s_setprio(1);
    f32x4 sc[2][4];
    for (int mt = 0; mt < 4; ++mt) {
      bf16x8 kf[4];
      for (int kc = 0; kc < 4; ++kc)
        kf[kc] = ld_bf8(&Kt[cur][(mt * 16 + c) * 136 + kc * 32 + q4 * 8]);
      for (int blk = 0; blk < 2; ++blk) {
        f32x4 s = {0.f, 0.f, 0.f, 0.f};
        for (int kc = 0; kc < 4; ++kc)
          s = __builtin_amdgcn_mfma_f32_16x16x32_bf16(kf[kc], qf[blk][kc], s, 0, 0, 0);
        sc[blk][mt] = s;
      }
    }
    __builtin_amdgcn_s_setprio(0);

    // softmax + plain-C bf16 pack (f2bf == the proven Pb path's rounding)
    unsigned int pw[2][4][2];                // [blk][mt][half]
#pragma unroll
    for (int blk = 0; blk < 2; ++blk) {
      float ts = 0.f;
#pragma unroll
      for (int mt = 0; mt < 4; ++mt) {
        f32x4 p;
        for (int r = 0; r < 4; ++r) { p[r] = __expf(sc[blk][mt][r]); ts += p[r]; }
        sc[blk][mt] = p;
      }
      lsum[blk] += ts;
#pragma unroll
      for (int mt = 0; mt < 4; ++mt) {
        pw[blk][mt][0] = (unsigned int)f2bf(sc[blk][mt][0]) |
                         ((unsigned int)f2bf(sc[blk][mt][1]) << 16);
        pw[blk][mt][1] = (unsigned int)f2bf(sc[blk][mt][2]) |
                         ((unsigned int)f2bf(sc[blk][mt][3]) << 16);
      }
    }

    // PV MFMA cluster (priority-boosted). Virtual key order:
    // vk = q4*8+j -> key = kc2*32 + (j<4 ? q4*4+j : 16+q4*4+(j-4)); V read
    // with the same map (two b64 at +0 / +16 shorts) -> key-sum exact.
    __builtin_amdgcn_s_setprio(1);
#pragma unroll
    for (int kc2 = 0; kc2 < 2; ++kc2) {
      u32x4 pa = {pw[0][2 * kc2][0], pw[0][2 * kc2][1],
                  pw[0][2 * kc2 + 1][0], pw[0][2 * kc2 + 1][1]};
      u32x4 pb = {pw[1][2 * kc2][0], pw[1][2 * kc2][1],
                  pw[1][2 * kc2 + 1][0], pw[1][2 * kc2 + 1][1]};
      bf16x8 pf0 = __builtin_bit_cast(bf16x8, pa);
      bf16x8 pf1 = __builtin_bit_cast(bf16x8, pb);
      for (int nt = 0; nt < 8; ++nt) {
        const unsigned short* vp = &VT[cur][(nt * 16 + c) * 72 + kc2 * 32 + q4 * 4];
        u16x4 vlo = *(const u16x4*)vp;         // keys kc2*32 + q4*4 + 0..3
        u16x4 vhi = *(const u16x4*)(vp + 16);  // keys kc2*32 + 16 + q4*4 + 0..3
        bf16x8 vf = __builtin_bit_cast(bf16x8,
            __builtin_shufflevector(vlo, vhi, 0, 1, 2, 3, 4, 5, 6, 7));
        acc[0][nt] = __builtin_amdgcn_mfma_f32_16x16x32_bf16(pf0, vf, acc[0][nt], 0, 0, 0);
        acc[1][nt] = __builtin_amdgcn_mfma_f32_16x16x32_bf16(pf1, vf, acc[1][nt], 0, 0, 0);
      }
    }
    __builtin_amdgcn_s_setprio(0);
    // no trailing barrier: next iter writes buf[cur^1]
  }

  unsigned short* ctxk = ctxp + (size_t)kb * SQ * HD;
  for (int blk = 0; blk < 2; ++blk) {
    float l = lsum[blk];
    l += __shfl_xor(l, 16);
    l += __shfl_xor(l, 32);
    float rl = 1.f / l;
    if (q4 == 0)
      lbuf[(size_t)kb * NHEADS * SQ + h * SQ + s0 + w * 32 + blk * 16 + c] = l;
    float r0 = __shfl(rl, q4 * 4 + 0);
    float r1 = __shfl(rl, q4 * 4 + 1);
    float r2 = __shfl(rl, q4 * 4 + 2);
    float r3 = __shfl(rl, q4 * 4 + 3);
    for (int nt = 0; nt < 8; ++nt) {
      int col = h * H + nt * 16 + c;
      int srow = s0 + w * 32 + blk * 16 + q4 * 4;
      ctxk[(size_t)(srow + 0) * HD + col] = f2bf(acc[blk][nt][0] * r0);
      ctxk[(size_t)(srow + 1) * HD + col] = f2bf(acc[blk][nt][1] * r1);
      ctxk[(size_t)(srow + 2) * HD + col] = f2bf(acc[blk][nt][2] * r2);
      ctxk[(size_t)(srow + 3) * HD + col] = f2bf(acc[blk][nt][3] * r3);
    }
  }
}

// ---------------- kernel 3: out = combine(ctxp) @ Wc + bc + x -------------
// grid 256 (16 rows/block): 4 waves split the 8 n-tiles (2 each, acc[2]).
__global__ __launch_bounds__(256) void out_kernel(
    const unsigned short* __restrict__ ctxp,
    const float* __restrict__ lbuf,
    const unsigned short* __restrict__ WcT,
    const float* __restrict__ bc,
    const float* __restrict__ x,
    float* __restrict__ out)
{
  __shared__ unsigned short At[16 * 136];
  __shared__ unsigned short Bt[128 * 136];
  const int tid = threadIdx.x;
  const int s0 = blockIdx.x * 16;
  const int lane = tid & 63, w = tid >> 6;
  const int c = lane & 15, q4 = lane >> 4;

  f32x4 acc[2];
  acc[0] = (f32x4){0.f, 0.f, 0.f, 0.f};
  acc[1] = (f32x4){0.f, 0.f, 0.f, 0.f};

  for (int kt = 0; kt < 8; ++kt) {         // head kt
    __syncthreads();
    {                                      // combine: one u16x8 per thread
      int row = tid >> 4, col8 = (tid & 15) * 8;
      const unsigned short* p0 = &ctxp[(size_t)(s0 + row) * HD + kt * 128 + col8];
      u16x8 a0 = *(const u16x8*)p0;
      u16x8 a1 = *(const u16x8*)(p0 + (size_t)SQ * HD);
      float la = lbuf[(size_t)kt * SQ + s0 + row];
      float lb = lbuf[(size_t)NHEADS * SQ + (size_t)kt * SQ + s0 + row];
      float ri = 1.f / (la + lb);
      float wa = la * ri, wb = lb * ri;
      u16x8 av;
      for (int e = 0; e < 8; ++e)
        av[e] = f2bf(wa * b2f(a0[e]) + wb * b2f(a1[e]));
      *(u16x8*)&At[row * 136 + col8] = av;
    }
    for (int i = 0; i < 8; ++i) {
      int ch = tid + i * 256;
      int row = ch >> 4, col8 = (ch & 15) * 8;
      *(u16x8*)&Bt[row * 136 + col8] =
          *(const u16x8*)&WcT[row * HD + kt * 128 + col8];
    }
    __syncthreads();
    bf16x8 af[4];
    for (int kc = 0; kc < 4; ++kc)
      af[kc] = ld_bf8(&At[c * 136 + kc * 32 + q4 * 8]);
    for (int j = 0; j < 2; ++j) {
      int nt = w * 2 + j;
      f32x4 a = acc[j];
      for (int kc = 0; kc < 4; ++kc) {
        bf16x8 bf = ld_bf8(&Bt[(nt * 16 + c) * 136 + kc * 32 + q4 * 8]);
        a = __builtin_amdgcn_mfma_f32_16x16x32_bf16(af[kc], bf, a, 0, 0, 0);
      }
      acc[j] = a;
    }
  }
  for (int j = 0; j < 2; ++j) {
    int nt = w * 2 + j;
    float bb = bc[nt * 16 + c];
    for (int r = 0; r < 4; ++r) {
      int srow = s0 + q4 * 4 + r;
      int col = nt * 16 + c;
      out[srow * H + col] = acc[j][r] + bb + x[srow * H + col];
    }
  }
}

extern "C" void kernel_launch(void* const* d_in, const int* in_sizes, int n_in,
                              void* d_out, int out_size, void* d_ws, size_t ws_size,
                              hipStream_t stream) {
  const float* x  = (const float*)d_in[0];
  const float* W1 = (const float*)d_in[1];
  const float* b1 = (const float*)d_in[2];
  const float* W2 = (const float*)d_in[3];
  const float* b2 = (const float*)d_in[4];
  const float* Wc = (const float*)d_in[5];
  const float* bc = (const float*)d_in[6];
  float* out = (float*)d_out;

  // Key-split layout (42,991,616 B) -- R10's proven 2-way layout.
  char* ws = (char*)d_ws;
  unsigned short* q1bf = (unsigned short*)ws; ws += (size_t)NHEADS * SQ * H * 2;
  unsigned short* q2K  = (unsigned short*)ws; ws += (size_t)NHEADS * SQ * H * 2;
  unsigned short* q2VT = (unsigned short*)ws; ws += (size_t)NHEADS * SQ * H * 2;
  unsigned short* ctxp = (unsigned short*)ws; ws += (size_t)2 * SQ * HD * 2;
  float*          lbuf = (float*)ws;          ws += (size_t)2 * NHEADS * SQ * 4;
  unsigned short* W1T  = (unsigned short*)ws; ws += (size_t)HD * H * 2;
  unsigned short* W2T  = (unsigned short*)ws; ws += (size_t)HD * H * 2;
  unsigned short* WcT  = (unsigned short*)ws; ws += (size_t)HD * H * 2;

  prep_kernel<<<64, 256, 0, stream>>>(W1, W2, Wc, W1T, W2T, WcT);
  proj_kernel<<<512, 256, 0, stream>>>(x, b1, b2, W1T, W2T, q1bf, q2K, q2VT);
  flash_kernel<<<512, 256, 0, stream>>>(q1bf, q2K, q2VT, ctxp, lbuf);
  out_kernel<<<256, 256, 0, stream>>>(ctxp, lbuf, WcT, bc, x, out);
}